// Round 1
// baseline (939.656 us; speedup 1.0000x reference)
//
#include <hip/hip_runtime.h>
#include <math.h>

// AdditiveAttention: B=64, L=1024, Q=K=H=1024, fp32 in/out.
// Round 5: move fp32->bf16 conversion OUT of k2's staging loop into a one-time
// pre-pass (workspace permitting), so k2 stages via global_load_lds width=16
// (the m93->m97 ladder step, +69% measured). Fallback to the verified reg-staged
// k2 when ws_size < 130 MB.
//
//   out[0..65536):      k0 zeroes; k1 atomicAdds q = query@W1^T; k3 zeroes; k4 accumulates context.
//   out[65536..131072): k0 zeroes; k2 atomicAdds scores; k3 overwrites with softmax weights.
//   ws (if >=130MB):    [0..67108864) keys as bf16; [67108864..68157440) W2 as bf16.

typedef __attribute__((ext_vector_type(8))) short short8;   // 8 bf16 = 4 VGPRs (A/B frag)
typedef __attribute__((ext_vector_type(4))) float floatx4;  // 4 fp32 (C/D frag)

__device__ __forceinline__ short f2bf(float x) {            // fp32 -> bf16, round-nearest-even
    unsigned u = __float_as_uint(x);
    u += 0x7fffu + ((u >> 16) & 1u);
    return (short)(u >> 16);
}
__device__ __forceinline__ short8 pack8(float4 lo, float4 hi) {
    short8 r;
    r[0]=f2bf(lo.x); r[1]=f2bf(lo.y); r[2]=f2bf(lo.z); r[3]=f2bf(lo.w);
    r[4]=f2bf(hi.x); r[5]=f2bf(hi.y); r[6]=f2bf(hi.z); r[7]=f2bf(hi.w);
    return r;
}
__device__ __forceinline__ void gload_lds16(const short* g, short* l) {
    // async 16B global->LDS DMA; LDS dest = wave-uniform base + lane*16 (linear)
    __builtin_amdgcn_global_load_lds(
        (const __attribute__((address_space(1))) unsigned int*)g,
        (__attribute__((address_space(3))) unsigned int*)l, 16, 0, 0);
}

#define LDA 40   // fallback-path staging pad (shorts)

// ---------------- k0: zero the whole output buffer (131072 floats) ----------------
__global__ __launch_bounds__(256) void k0_zero(float* __restrict__ out) {
    const int i = (blockIdx.x * 256 + threadIdx.x) * 4;
    const float4 z = {0.f, 0.f, 0.f, 0.f};
    *(float4*)(out + i) = z;
}

// ------- k1: q += query @ W1^T (BM=64 b, BN=64 h, BK=32), K split x4, atomicAdd -------
__global__ __launch_bounds__(256) void k1_qproj(
    const float* __restrict__ query, const float* __restrict__ W1,
    float* __restrict__ out)
{
    __shared__ float As[32][64];   // [k][b]
    __shared__ float Bs[32][64];   // [k][h]
    const int t  = threadIdx.x;
    const int tx = t & 15, ty = t >> 4;
    const int h0 = blockIdx.x * 64;
    const int kbase = blockIdx.y * 256;
    const int sr = t >> 2;          // staging row 0..63
    const int sk = (t & 3) * 8;     // staging k offset {0,8,16,24}
    float c[4][4] = {{0.f}};
    for (int k0 = kbase; k0 < kbase + 256; k0 += 32) {
        const float4 a0 = *(const float4*)(query + sr * 1024 + k0 + sk);
        const float4 a1 = *(const float4*)(query + sr * 1024 + k0 + sk + 4);
        const float4 b0 = *(const float4*)(W1 + (h0 + sr) * 1024 + k0 + sk);
        const float4 b1 = *(const float4*)(W1 + (h0 + sr) * 1024 + k0 + sk + 4);
        __syncthreads();
        As[sk+0][sr]=a0.x; As[sk+1][sr]=a0.y; As[sk+2][sr]=a0.z; As[sk+3][sr]=a0.w;
        As[sk+4][sr]=a1.x; As[sk+5][sr]=a1.y; As[sk+6][sr]=a1.z; As[sk+7][sr]=a1.w;
        Bs[sk+0][sr]=b0.x; Bs[sk+1][sr]=b0.y; Bs[sk+2][sr]=b0.z; Bs[sk+3][sr]=b0.w;
        Bs[sk+4][sr]=b1.x; Bs[sk+5][sr]=b1.y; Bs[sk+6][sr]=b1.z; Bs[sk+7][sr]=b1.w;
        __syncthreads();
        #pragma unroll
        for (int k = 0; k < 32; ++k) {
            const float4 av = *(const float4*)&As[k][ty*4];
            const float4 bv = *(const float4*)&Bs[k][tx*4];
            const float aa[4] = {av.x, av.y, av.z, av.w};
            const float bb[4] = {bv.x, bv.y, bv.z, bv.w};
            #pragma unroll
            for (int i = 0; i < 4; ++i)
                #pragma unroll
                for (int j = 0; j < 4; ++j)
                    c[i][j] = fmaf(aa[i], bb[j], c[i][j]);
        }
    }
    #pragma unroll
    for (int i = 0; i < 4; ++i)
        #pragma unroll
        for (int j = 0; j < 4; ++j)
            atomicAdd(&out[(ty*4 + i) * 1024 + h0 + tx*4 + j], c[i][j]);
}

// ---------------- k_cvt: fp32 -> bf16 (RNE), 8 elements per thread-task ----------------
__global__ __launch_bounds__(256) void k_cvt(const float* __restrict__ src,
                                             short* __restrict__ dst, int n8)
{
    const int stride = gridDim.x * 256;
    for (int i = blockIdx.x * 256 + threadIdx.x; i < n8; i += stride) {
        const float4 a = ((const float4*)src)[(size_t)i * 2];
        const float4 b = ((const float4*)src)[(size_t)i * 2 + 1];
        ((short8*)dst)[i] = pack8(a, b);
    }
}

// --------- k2 (async): bf16 keys/W2 via global_load_lds, m97 structure ---------
// grid (hb=8 fastest, l-tile=8, b=64); block 256 thr = 4 waves; tile 128l x 128h, BK=32.
// LDS linear [128][32] bf16 for A and B (global_load_lds requires linear dest).
__global__ __launch_bounds__(256) void k2_scores_async(
    const short* __restrict__ keysb, const short* __restrict__ W2b,
    const float* __restrict__ v, float* __restrict__ out)
{
    __shared__ union {
        struct { short A[128 * 32]; short B[128 * 32]; } st;  // 16 KB DMA staging
        float red[128][33];                                    // 16.9 KB epilogue overlay
    } sm;
    const int t  = threadIdx.x;
    const int hb = blockIdx.x;          // 0..7 (fastest: pins one W2 tile per XCD L2)
    const int l0 = blockIdx.y * 128;
    const int b  = blockIdx.z;
    const int h0 = hb * 128;
    const float* q = out;               // written by k1
    float* score = out + 65536;         // zeroed by k0

    const int lane = t & 63, wid = t >> 6;
    const int quad = lane >> 4, m16 = lane & 15;
    const int wm = (wid >> 1) * 64;     // wave's m (l) origin
    const int wn = (wid & 1) * 64;      // wave's n (h) origin

    // wave wid stages rows [wid*32, wid*32+32) of A and of B, 16 rows (1 KB) per call.
    // lane l covers row base + l/4, k-offset (l&3)*8 -> matches HW's base + lane*16B.
    const int r0  = wid * 32 + (lane >> 2);
    const int kof = (lane & 3) * 8;
    const short* gA = keysb + ((size_t)(b * 1024 + l0 + r0)) * 1024 + kof;
    const short* gB = W2b  + ((size_t)(h0 + r0)) * 1024 + kof;
    short* lA = sm.st.A + (wid * 32) * 32;   // wave-uniform LDS bases
    short* lB = sm.st.B + (wid * 32) * 32;

    floatx4 acc[4][4] = {};
    for (int kk = 0; kk < 1024; kk += 32) {
        __syncthreads();                     // prior frag reads done before DMA overwrite
        gload_lds16(gA + kk,             lA);
        gload_lds16(gA + 16 * 1024 + kk, lA + 16 * 32);
        gload_lds16(gB + kk,             lB);
        gload_lds16(gB + 16 * 1024 + kk, lB + 16 * 32);
        __syncthreads();                     // implicit vmcnt(0): DMA data landed
        short8 af[4], bf[4];
        #pragma unroll
        for (int i = 0; i < 4; ++i)
            af[i] = *(const short8*)(sm.st.A + (wm + i * 16 + m16) * 32 + quad * 8);
        #pragma unroll
        for (int j = 0; j < 4; ++j)
            bf[j] = *(const short8*)(sm.st.B + (wn + j * 16 + m16) * 32 + quad * 8);
        #pragma unroll
        for (int i = 0; i < 4; ++i)
            #pragma unroll
            for (int j = 0; j < 4; ++j)
                acc[i][j] = __builtin_amdgcn_mfma_f32_16x16x32_bf16(af[i], bf[j], acc[i][j], 0, 0, 0);
    }

    // epilogue: s[l] = sum_h tanh(q[b,h] + D[l,h]) * v[h] over this block's 128 h
    float qv[4], vv[4];
    #pragma unroll
    for (int j = 0; j < 4; ++j) {
        const int h = h0 + wn + j * 16 + m16;   // C/D col for n-tile j
        qv[j] = q[b * 1024 + h];
        vv[j] = v[h];
    }
    __syncthreads();   // staging reads done before red overlay
    #pragma unroll
    for (int i = 0; i < 4; ++i) {
        #pragma unroll
        for (int r = 0; r < 4; ++r) {
            float s = 0.f;
            #pragma unroll
            for (int j = 0; j < 4; ++j)
                s += tanhf(qv[j] + acc[i][j][r]) * vv[j];
            sm.red[wm + i * 16 + quad * 4 + r][(wid & 1) * 16 + m16] = s;
        }
    }
    __syncthreads();
    if (t < 128) {
        const float* rr = sm.red[t];
        float s = 0.f;
        #pragma unroll
        for (int c = 0; c < 32; ++c) s += rr[c];
        atomicAdd(&score[b * 1024 + l0 + t], s);   // accumulate over 8 hb blocks
    }
}

// --------- k2 (fallback): verified reg-staged variant, unchanged ---------
__global__ __launch_bounds__(256) void k2_scores(
    const float* __restrict__ keys, const float* __restrict__ W2,
    const float* __restrict__ v, float* __restrict__ out)
{
    __shared__ union {
        struct { short A[128][LDA]; short B[128][LDA]; } st;  // 20.0 KB staging
        float red[128][33];                                    // 16.5 KB epilogue overlay
    } sm;
    const int t  = threadIdx.x;
    const int hb = blockIdx.x;          // 0..7
    const int l0 = blockIdx.y * 128;
    const int b  = blockIdx.z;
    const int h0 = hb * 128;
    const float* q = out;               // written by k1
    float* score = out + 65536;         // zeroed by k0

    const int srow = t >> 1;
    const int skh  = (t & 1) * 16;
    const float* Arow = keys + ((size_t)(b * 1024 + l0 + srow)) * 1024 + skh;
    const float* Brow = W2   + ((size_t)(h0 + srow)) * 1024 + skh;

    const int lane = t & 63, wid = t >> 6;
    const int quad = lane >> 4, m16 = lane & 15;
    const int wm = (wid >> 1) * 64;
    const int wn = (wid & 1) * 64;

    floatx4 acc[4][4] = {};

    for (int kk = 0; kk < 1024; kk += 32) {
        const float4 a0 = *(const float4*)(Arow + kk);
        const float4 a1 = *(const float4*)(Arow + kk + 4);
        const float4 a2 = *(const float4*)(Arow + kk + 8);
        const float4 a3 = *(const float4*)(Arow + kk + 12);
        const float4 w0 = *(const float4*)(Brow + kk);
        const float4 w1 = *(const float4*)(Brow + kk + 4);
        const float4 w2 = *(const float4*)(Brow + kk + 8);
        const float4 w3 = *(const float4*)(Brow + kk + 12);
        __syncthreads();
        *(short8*)&sm.st.A[srow][skh]     = pack8(a0, a1);
        *(short8*)&sm.st.A[srow][skh + 8] = pack8(a2, a3);
        *(short8*)&sm.st.B[srow][skh]     = pack8(w0, w1);
        *(short8*)&sm.st.B[srow][skh + 8] = pack8(w2, w3);
        __syncthreads();
        short8 af[4], bf[4];
        #pragma unroll
        for (int i = 0; i < 4; ++i)
            af[i] = *(const short8*)&sm.st.A[wm + i*16 + m16][quad * 8];
        #pragma unroll
        for (int j = 0; j < 4; ++j)
            bf[j] = *(const short8*)&sm.st.B[wn + j*16 + m16][quad * 8];
        #pragma unroll
        for (int i = 0; i < 4; ++i)
            #pragma unroll
            for (int j = 0; j < 4; ++j)
                acc[i][j] = __builtin_amdgcn_mfma_f32_16x16x32_bf16(af[i], bf[j], acc[i][j], 0, 0, 0);
    }

    float qv[4], vv[4];
    #pragma unroll
    for (int j = 0; j < 4; ++j) {
        const int h = h0 + wn + j * 16 + m16;
        qv[j] = q[b * 1024 + h];
        vv[j] = v[h];
    }
    __syncthreads();
    #pragma unroll
    for (int i = 0; i < 4; ++i) {
        #pragma unroll
        for (int r = 0; r < 4; ++r) {
            float s = 0.f;
            #pragma unroll
            for (int j = 0; j < 4; ++j)
                s += tanhf(qv[j] + acc[i][j][r]) * vv[j];
            sm.red[wm + i * 16 + quad * 4 + r][(wid & 1) * 16 + m16] = s;
        }
    }
    __syncthreads();
    if (t < 128) {
        const float* rr = sm.red[t];
        float s = 0.f;
        #pragma unroll
        for (int c = 0; c < 32; ++c) s += rr[c];
        atomicAdd(&score[b * 1024 + l0 + t], s);
    }
}

// --------- k3: mask, softmax in-place over score region; zero context row ---------
__global__ __launch_bounds__(256) void k3_softmax(
    const unsigned char* __restrict__ mask_u8, float* __restrict__ out)
{
    __shared__ float sc[1024];
    __shared__ float red[256];
    __shared__ int nz_sh;
    const int b = blockIdx.x;
    const int t = threadIdx.x;

    if (t == 0) nz_sh = 0;
    __syncthreads();
    {
        int nz = 0;
        #pragma unroll
        for (int j = 1; j < 4; ++j)
            if (mask_u8[t * 4 + j] != 0) nz = 1;
        if (nz) atomicAdd(&nz_sh, 1);
    }
    __syncthreads();
    const int use_i32 = (nz_sh == 0);
    const int* mask_i32 = (const int*)mask_u8;

    float* score = out + 65536;
    float lmax = -INFINITY;
    #pragma unroll
    for (int i = 0; i < 4; ++i) {
        const int l = t + i * 256;
        float s = score[b * 1024 + l];
        const int ml = b * 1024 + l;
        const bool masked = use_i32 ? (mask_i32[ml] != 0) : (mask_u8[ml] != 0);
        if (masked) s = -INFINITY;
        sc[l] = s;
        lmax = fmaxf(lmax, s);
    }
    red[t] = lmax;
    __syncthreads();
    for (int off = 128; off > 0; off >>= 1) {
        if (t < off) red[t] = fmaxf(red[t], red[t + off]);
        __syncthreads();
    }
    const float m = red[0];
    __syncthreads();
    float e[4];
    float lsum = 0.f;
    #pragma unroll
    for (int i = 0; i < 4; ++i) {
        const float s = sc[t + i * 256];
        const float ev = (s > -INFINITY && m > -INFINITY) ? expf(s - m) : 0.f;
        e[i] = ev;
        lsum += ev;
    }
    red[t] = lsum;
    __syncthreads();
    for (int off = 128; off > 0; off >>= 1) {
        if (t < off) red[t] += red[t + off];
        __syncthreads();
    }
    const float S = red[0];
    const float inv = (S > 0.f) ? (1.f / S) : 0.f;
    #pragma unroll
    for (int i = 0; i < 4; ++i)
        score[b * 1024 + t + i * 256] = e[i] * inv;
    const float4 z = {0.f, 0.f, 0.f, 0.f};
    ((float4*)(out + b * 1024))[t] = z;
}

// --------- k4: context[b,:] += sum over this block's 128 l's of w*keys ---------
__global__ __launch_bounds__(256) void k4_context(
    const float* __restrict__ keys, float* __restrict__ out)
{
    __shared__ float w[128];
    const int t  = threadIdx.x;
    const int b  = blockIdx.y;
    const int l0 = blockIdx.x * 128;
    if (t < 128) w[t] = out[65536 + b * 1024 + l0 + t];
    __syncthreads();
    const float4* kp = (const float4*)(keys + ((size_t)b * 1024 + (size_t)l0) * 1024) + t;
    float4 acc = {0.f, 0.f, 0.f, 0.f};
    #pragma unroll 4
    for (int l = 0; l < 128; ++l) {
        const float4 kv = kp[(size_t)l * 256];
        const float wv = w[l];
        acc.x = fmaf(wv, kv.x, acc.x);
        acc.y = fmaf(wv, kv.y, acc.y);
        acc.z = fmaf(wv, kv.z, acc.z);
        acc.w = fmaf(wv, kv.w, acc.w);
    }
    float* o = out + b * 1024 + t * 4;
    atomicAdd(o + 0, acc.x);
    atomicAdd(o + 1, acc.y);
    atomicAdd(o + 2, acc.z);
    atomicAdd(o + 3, acc.w);
}

extern "C" void kernel_launch(void* const* d_in, const int* in_sizes, int n_in,
                              void* d_out, int out_size, void* d_ws, size_t ws_size,
                              hipStream_t stream) {
    const float*         query = (const float*)d_in[0];
    const float*         keys  = (const float*)d_in[1];
    const unsigned char* mask  = (const unsigned char*)d_in[2];  // bool: u8 or i32, sniffed in k3
    const float*         W1    = (const float*)d_in[3];
    const float*         W2    = (const float*)d_in[4];
    const float*         v     = (const float*)d_in[5];
    float* out = (float*)d_out;   // [0..65536) context, [65536..131072) weights

    const size_t KEYS_BF = (size_t)64 * 1024 * 1024 * 2;   // 134,217,728 B
    const size_t W2_BF   = (size_t)1024 * 1024 * 2;        //   2,097,152 B
    const bool use_ws = (d_ws != nullptr) && (ws_size >= KEYS_BF + W2_BF);

    k0_zero   <<<dim3(128),       256, 0, stream>>>(out);
    k1_qproj  <<<dim3(16, 4),     256, 0, stream>>>(query, W1, out);
    if (use_ws) {
        short* keysb = (short*)d_ws;
        short* W2b   = keysb + KEYS_BF / 2;   // 16B-aligned (KEYS_BF % 16 == 0)
        k_cvt <<<dim3(2048), 256, 0, stream>>>(keys, keysb, 8388608);   // 64*1024*1024/8
        k_cvt <<<dim3(512),  256, 0, stream>>>(W2,   W2b,   131072);    // 1024*1024/8
        k2_scores_async<<<dim3(8, 8, 64), 256, 0, stream>>>(keysb, W2b, v, out);
    } else {
        k2_scores      <<<dim3(8, 8, 64), 256, 0, stream>>>(keys, W2, v, out);
    }
    k3_softmax<<<dim3(64),        256, 0, stream>>>(mask, out);
    k4_context<<<dim3(8, 64),     256, 0, stream>>>(keys, out);
}

// Round 2
// 667.101 us; speedup vs baseline: 1.4086x; 1.4086x over previous
//
#include <hip/hip_runtime.h>
#include <math.h>

// AdditiveAttention: B=64, L=1024, Q=K=H=1024, fp32 in/out.
// Round 6: k2's LDS staging was bank-conflict-bound (2.35e8 conflict cycles,
// 75% of CU time). Fix: pre-pack keys/W2 into MFMA-fragment order in the
// workspace, so k2 loads A/B fragments DIRECTLY global->VGPR (coalesced 1KB
// per wave-instr), no LDS staging, no main-loop barriers. 2-deep SW pipeline.
//
//   out[0..65536):      k0 zeroes; k1 atomicAdds q = query@W1^T; k3 zeroes; k4 accumulates context.
//   out[65536..131072): k0 zeroes; k2 atomicAdds scores; k3 overwrites with softmax weights.
//   ws (if >=130MB):    [0..) keys packed bf16; [+134217728B..) W2 packed bf16.
//   Packed layout: [panel = row/16][chunk = k/8][m = row%16][8 bf16]
//     -> fragment (row, k..k+8) for lane (quad,m16) is 16 contiguous bytes.

typedef __attribute__((ext_vector_type(8))) short short8;   // 8 bf16 = 4 VGPRs (A/B frag)
typedef __attribute__((ext_vector_type(4))) float floatx4;  // 4 fp32 (C/D frag)

__device__ __forceinline__ short f2bf(float x) {            // fp32 -> bf16, round-nearest-even
    unsigned u = __float_as_uint(x);
    u += 0x7fffu + ((u >> 16) & 1u);
    return (short)(u >> 16);
}
__device__ __forceinline__ short8 pack8(float4 lo, float4 hi) {
    short8 r;
    r[0]=f2bf(lo.x); r[1]=f2bf(lo.y); r[2]=f2bf(lo.z); r[3]=f2bf(lo.w);
    r[4]=f2bf(hi.x); r[5]=f2bf(hi.y); r[6]=f2bf(hi.z); r[7]=f2bf(hi.w);
    return r;
}

#define LDA 40   // fallback-path staging pad (shorts)

// ---------------- k0: zero the whole output buffer (131072 floats) ----------------
__global__ __launch_bounds__(256) void k0_zero(float* __restrict__ out) {
    const int i = (blockIdx.x * 256 + threadIdx.x) * 4;
    const float4 z = {0.f, 0.f, 0.f, 0.f};
    *(float4*)(out + i) = z;
}

// ------- k1: q += query @ W1^T (BM=64 b, BN=64 h, BK=32), K split x4, atomicAdd -------
__global__ __launch_bounds__(256) void k1_qproj(
    const float* __restrict__ query, const float* __restrict__ W1,
    float* __restrict__ out)
{
    __shared__ float As[32][64];   // [k][b]
    __shared__ float Bs[32][64];   // [k][h]
    const int t  = threadIdx.x;
    const int tx = t & 15, ty = t >> 4;
    const int h0 = blockIdx.x * 64;
    const int kbase = blockIdx.y * 256;
    const int sr = t >> 2;          // staging row 0..63
    const int sk = (t & 3) * 8;     // staging k offset {0,8,16,24}
    float c[4][4] = {{0.f}};
    for (int k0 = kbase; k0 < kbase + 256; k0 += 32) {
        const float4 a0 = *(const float4*)(query + sr * 1024 + k0 + sk);
        const float4 a1 = *(const float4*)(query + sr * 1024 + k0 + sk + 4);
        const float4 b0 = *(const float4*)(W1 + (h0 + sr) * 1024 + k0 + sk);
        const float4 b1 = *(const float4*)(W1 + (h0 + sr) * 1024 + k0 + sk + 4);
        __syncthreads();
        As[sk+0][sr]=a0.x; As[sk+1][sr]=a0.y; As[sk+2][sr]=a0.z; As[sk+3][sr]=a0.w;
        As[sk+4][sr]=a1.x; As[sk+5][sr]=a1.y; As[sk+6][sr]=a1.z; As[sk+7][sr]=a1.w;
        Bs[sk+0][sr]=b0.x; Bs[sk+1][sr]=b0.y; Bs[sk+2][sr]=b0.z; Bs[sk+3][sr]=b0.w;
        Bs[sk+4][sr]=b1.x; Bs[sk+5][sr]=b1.y; Bs[sk+6][sr]=b1.z; Bs[sk+7][sr]=b1.w;
        __syncthreads();
        #pragma unroll
        for (int k = 0; k < 32; ++k) {
            const float4 av = *(const float4*)&As[k][ty*4];
            const float4 bv = *(const float4*)&Bs[k][tx*4];
            const float aa[4] = {av.x, av.y, av.z, av.w};
            const float bb[4] = {bv.x, bv.y, bv.z, bv.w};
            #pragma unroll
            for (int i = 0; i < 4; ++i)
                #pragma unroll
                for (int j = 0; j < 4; ++j)
                    c[i][j] = fmaf(aa[i], bb[j], c[i][j]);
        }
    }
    #pragma unroll
    for (int i = 0; i < 4; ++i)
        #pragma unroll
        for (int j = 0; j < 4; ++j)
            atomicAdd(&out[(ty*4 + i) * 1024 + h0 + tx*4 + j], c[i][j]);
}

// ---- k_pack: fp32 [R][1024] -> bf16 packed [R/16][128][16][8], RNE ----
// out unit o (16B): m=o&15, c=(o>>4)&127, panel=o>>11; row = panel*16+m; k0 = c*8.
// Wave reads 16 full 128B lines (fully consumed); writes 1KB contiguous.
__global__ __launch_bounds__(256) void k_pack(const float* __restrict__ src,
                                              short* __restrict__ dst, int nunits)
{
    const int stride = gridDim.x * 256;
    for (int o = blockIdx.x * 256 + threadIdx.x; o < nunits; o += stride) {
        const int m = o & 15;
        const int c = (o >> 4) & 127;
        const int panel = o >> 11;
        const size_t f = ((size_t)panel * 16 + m) * 1024 + c * 8;
        const float4 a = *(const float4*)(src + f);
        const float4 b = *(const float4*)(src + f + 4);
        ((short8*)dst)[o] = pack8(a, b);
    }
}

// --------- k2 (direct): fragment loads straight from packed global, no LDS staging ---------
// grid (hb=8, l-tile=8, b=64); block 256 thr = 4 waves; tile 128l x 128h over K=1024.
// Barrier-free main loop, 2-deep SW pipeline (load kk+32 under MFMA of kk).
__global__ __launch_bounds__(256) void k2_scores_direct(
    const short* __restrict__ keysp, const short* __restrict__ W2p,
    const float* __restrict__ v, float* __restrict__ out)
{
    __shared__ float red[128][33];      // epilogue reduction only (16.9 KB)
    const int t  = threadIdx.x;
    const int hb = blockIdx.x;          // 0..7
    const int l0 = blockIdx.y * 128;
    const int b  = blockIdx.z;
    const int h0 = hb * 128;
    const float* q = out;               // written by k1
    float* score = out + 65536;         // zeroed by k0

    const int lane = t & 63, wid = t >> 6;
    const int quad = lane >> 4, m16 = lane & 15;
    const int wm = (wid >> 1) * 64;     // wave's m (l) origin
    const int wn = (wid & 1) * 64;      // wave's n (h) origin

    // per-lane fragment pointers in short8 units (panel = 2048 units = 32 KB)
    const short8* pA = (const short8*)keysp
        + ((size_t)(b * 64 + (l0 >> 4) + (wm >> 4))) * 2048 + quad * 16 + m16;
    const short8* pB = (const short8*)W2p
        + ((size_t)((h0 >> 4) + (wn >> 4))) * 2048 + quad * 16 + m16;

    floatx4 acc[4][4] = {};
    short8 a0[4], b0[4], a1[4], b1[4];

    #pragma unroll
    for (int i = 0; i < 4; ++i) { a0[i] = pA[i * 2048]; b0[i] = pB[i * 2048]; }

    for (int kk = 0; kk < 928; kk += 64) {
        #pragma unroll
        for (int i = 0; i < 4; ++i) {
            a1[i] = pA[i * 2048 + (kk + 32) * 2];
            b1[i] = pB[i * 2048 + (kk + 32) * 2];
        }
        #pragma unroll
        for (int i = 0; i < 4; ++i)
            #pragma unroll
            for (int j = 0; j < 4; ++j)
                acc[i][j] = __builtin_amdgcn_mfma_f32_16x16x32_bf16(a0[i], b0[j], acc[i][j], 0, 0, 0);
        #pragma unroll
        for (int i = 0; i < 4; ++i) {
            a0[i] = pA[i * 2048 + (kk + 64) * 2];
            b0[i] = pB[i * 2048 + (kk + 64) * 2];
        }
        #pragma unroll
        for (int i = 0; i < 4; ++i)
            #pragma unroll
            for (int j = 0; j < 4; ++j)
                acc[i][j] = __builtin_amdgcn_mfma_f32_16x16x32_bf16(a1[i], b1[j], acc[i][j], 0, 0, 0);
    }
    // tail: a0/b0 hold kk=960; load 992, compute both
    #pragma unroll
    for (int i = 0; i < 4; ++i) {
        a1[i] = pA[i * 2048 + 992 * 2];
        b1[i] = pB[i * 2048 + 992 * 2];
    }
    #pragma unroll
    for (int i = 0; i < 4; ++i)
        #pragma unroll
        for (int j = 0; j < 4; ++j)
            acc[i][j] = __builtin_amdgcn_mfma_f32_16x16x32_bf16(a0[i], b0[j], acc[i][j], 0, 0, 0);
    #pragma unroll
    for (int i = 0; i < 4; ++i)
        #pragma unroll
        for (int j = 0; j < 4; ++j)
            acc[i][j] = __builtin_amdgcn_mfma_f32_16x16x32_bf16(a1[i], b1[j], acc[i][j], 0, 0, 0);

    // epilogue: s[l] = sum_h tanh(q[b,h] + D[l,h]) * v[h] over this block's 128 h
    float qv[4], vv[4];
    #pragma unroll
    for (int j = 0; j < 4; ++j) {
        const int h = h0 + wn + j * 16 + m16;   // C/D col for n-tile j
        qv[j] = q[b * 1024 + h];
        vv[j] = v[h];
    }
    #pragma unroll
    for (int i = 0; i < 4; ++i) {
        #pragma unroll
        for (int r = 0; r < 4; ++r) {
            float s = 0.f;
            #pragma unroll
            for (int j = 0; j < 4; ++j)
                s += tanhf(qv[j] + acc[i][j][r]) * vv[j];
            // C/D row for m-tile i, reg r: wm + i*16 + quad*4 + r
            red[wm + i * 16 + quad * 4 + r][(wid & 1) * 16 + m16] = s;
        }
    }
    __syncthreads();
    if (t < 128) {
        const float* rr = red[t];
        float s = 0.f;
        #pragma unroll
        for (int c = 0; c < 32; ++c) s += rr[c];
        atomicAdd(&score[b * 1024 + l0 + t], s);   // accumulate over 8 hb blocks
    }
}

// --------- k2 (fallback): verified reg-staged variant, unchanged ---------
__global__ __launch_bounds__(256) void k2_scores(
    const float* __restrict__ keys, const float* __restrict__ W2,
    const float* __restrict__ v, float* __restrict__ out)
{
    __shared__ union {
        struct { short A[128][LDA]; short B[128][LDA]; } st;  // 20.0 KB staging
        float red[128][33];                                    // 16.5 KB epilogue overlay
    } sm;
    const int t  = threadIdx.x;
    const int hb = blockIdx.x;          // 0..7
    const int l0 = blockIdx.y * 128;
    const int b  = blockIdx.z;
    const int h0 = hb * 128;
    const float* q = out;               // written by k1
    float* score = out + 65536;         // zeroed by k0

    const int srow = t >> 1;
    const int skh  = (t & 1) * 16;
    const float* Arow = keys + ((size_t)(b * 1024 + l0 + srow)) * 1024 + skh;
    const float* Brow = W2   + ((size_t)(h0 + srow)) * 1024 + skh;

    const int lane = t & 63, wid = t >> 6;
    const int quad = lane >> 4, m16 = lane & 15;
    const int wm = (wid >> 1) * 64;
    const int wn = (wid & 1) * 64;

    floatx4 acc[4][4] = {};

    for (int kk = 0; kk < 1024; kk += 32) {
        const float4 a0 = *(const float4*)(Arow + kk);
        const float4 a1 = *(const float4*)(Arow + kk + 4);
        const float4 a2 = *(const float4*)(Arow + kk + 8);
        const float4 a3 = *(const float4*)(Arow + kk + 12);
        const float4 w0 = *(const float4*)(Brow + kk);
        const float4 w1 = *(const float4*)(Brow + kk + 4);
        const float4 w2 = *(const float4*)(Brow + kk + 8);
        const float4 w3 = *(const float4*)(Brow + kk + 12);
        __syncthreads();
        *(short8*)&sm.st.A[srow][skh]     = pack8(a0, a1);
        *(short8*)&sm.st.A[srow][skh + 8] = pack8(a2, a3);
        *(short8*)&sm.st.B[srow][skh]     = pack8(w0, w1);
        *(short8*)&sm.st.B[srow][skh + 8] = pack8(w2, w3);
        __syncthreads();
        short8 af[4], bf[4];
        #pragma unroll
        for (int i = 0; i < 4; ++i)
            af[i] = *(const short8*)&sm.st.A[wm + i*16 + m16][quad * 8];
        #pragma unroll
        for (int j = 0; j < 4; ++j)
            bf[j] = *(const short8*)&sm.st.B[wn + j*16 + m16][quad * 8];
        #pragma unroll
        for (int i = 0; i < 4; ++i)
            #pragma unroll
            for (int j = 0; j < 4; ++j)
                acc[i][j] = __builtin_amdgcn_mfma_f32_16x16x32_bf16(af[i], bf[j], acc[i][j], 0, 0, 0);
    }

    float qv[4], vv[4];
    #pragma unroll
    for (int j = 0; j < 4; ++j) {
        const int h = h0 + wn + j * 16 + m16;
        qv[j] = q[b * 1024 + h];
        vv[j] = v[h];
    }
    __syncthreads();
    #pragma unroll
    for (int i = 0; i < 4; ++i) {
        #pragma unroll
        for (int r = 0; r < 4; ++r) {
            float s = 0.f;
            #pragma unroll
            for (int j = 0; j < 4; ++j)
                s += tanhf(qv[j] + acc[i][j][r]) * vv[j];
            sm.red[wm + i * 16 + quad * 4 + r][(wid & 1) * 16 + m16] = s;
        }
    }
    __syncthreads();
    if (t < 128) {
        const float* rr = sm.red[t];
        float s = 0.f;
        #pragma unroll
        for (int c = 0; c < 32; ++c) s += rr[c];
        atomicAdd(&score[b * 1024 + l0 + t], s);
    }
}

// --------- k3: mask, softmax in-place over score region; zero context row ---------
__global__ __launch_bounds__(256) void k3_softmax(
    const unsigned char* __restrict__ mask_u8, float* __restrict__ out)
{
    __shared__ float sc[1024];
    __shared__ float red[256];
    __shared__ int nz_sh;
    const int b = blockIdx.x;
    const int t = threadIdx.x;

    if (t == 0) nz_sh = 0;
    __syncthreads();
    {
        int nz = 0;
        #pragma unroll
        for (int j = 1; j < 4; ++j)
            if (mask_u8[t * 4 + j] != 0) nz = 1;
        if (nz) atomicAdd(&nz_sh, 1);
    }
    __syncthreads();
    const int use_i32 = (nz_sh == 0);
    const int* mask_i32 = (const int*)mask_u8;

    float* score = out + 65536;
    float lmax = -INFINITY;
    #pragma unroll
    for (int i = 0; i < 4; ++i) {
        const int l = t + i * 256;
        float s = score[b * 1024 + l];
        const int ml = b * 1024 + l;
        const bool masked = use_i32 ? (mask_i32[ml] != 0) : (mask_u8[ml] != 0);
        if (masked) s = -INFINITY;
        sc[l] = s;
        lmax = fmaxf(lmax, s);
    }
    red[t] = lmax;
    __syncthreads();
    for (int off = 128; off > 0; off >>= 1) {
        if (t < off) red[t] = fmaxf(red[t], red[t + off]);
        __syncthreads();
    }
    const float m = red[0];
    __syncthreads();
    float e[4];
    float lsum = 0.f;
    #pragma unroll
    for (int i = 0; i < 4; ++i) {
        const float s = sc[t + i * 256];
        const float ev = (s > -INFINITY && m > -INFINITY) ? expf(s - m) : 0.f;
        e[i] = ev;
        lsum += ev;
    }
    red[t] = lsum;
    __syncthreads();
    for (int off = 128; off > 0; off >>= 1) {
        if (t < off) red[t] += red[t + off];
        __syncthreads();
    }
    const float S = red[0];
    const float inv = (S > 0.f) ? (1.f / S) : 0.f;
    #pragma unroll
    for (int i = 0; i < 4; ++i)
        score[b * 1024 + t + i * 256] = e[i] * inv;
    const float4 z = {0.f, 0.f, 0.f, 0.f};
    ((float4*)(out + b * 1024))[t] = z;
}

// --------- k4: context[b,:] += sum over this block's 128 l's of w*keys ---------
__global__ __launch_bounds__(256) void k4_context(
    const float* __restrict__ keys, float* __restrict__ out)
{
    __shared__ float w[128];
    const int t  = threadIdx.x;
    const int b  = blockIdx.y;
    const int l0 = blockIdx.x * 128;
    if (t < 128) w[t] = out[65536 + b * 1024 + l0 + t];
    __syncthreads();
    const float4* kp = (const float4*)(keys + ((size_t)b * 1024 + (size_t)l0) * 1024) + t;
    float4 acc = {0.f, 0.f, 0.f, 0.f};
    #pragma unroll 4
    for (int l = 0; l < 128; ++l) {
        const float4 kv = kp[(size_t)l * 256];
        const float wv = w[l];
        acc.x = fmaf(wv, kv.x, acc.x);
        acc.y = fmaf(wv, kv.y, acc.y);
        acc.z = fmaf(wv, kv.z, acc.z);
        acc.w = fmaf(wv, kv.w, acc.w);
    }
    float* o = out + b * 1024 + t * 4;
    atomicAdd(o + 0, acc.x);
    atomicAdd(o + 1, acc.y);
    atomicAdd(o + 2, acc.z);
    atomicAdd(o + 3, acc.w);
}

extern "C" void kernel_launch(void* const* d_in, const int* in_sizes, int n_in,
                              void* d_out, int out_size, void* d_ws, size_t ws_size,
                              hipStream_t stream) {
    const float*         query = (const float*)d_in[0];
    const float*         keys  = (const float*)d_in[1];
    const unsigned char* mask  = (const unsigned char*)d_in[2];  // bool: u8 or i32, sniffed in k3
    const float*         W1    = (const float*)d_in[3];
    const float*         W2    = (const float*)d_in[4];
    const float*         v     = (const float*)d_in[5];
    float* out = (float*)d_out;   // [0..65536) context, [65536..131072) weights

    const size_t KEYS_BF = (size_t)64 * 1024 * 1024 * 2;   // 134,217,728 B
    const size_t W2_BF   = (size_t)1024 * 1024 * 2;        //   2,097,152 B
    const bool use_ws = (d_ws != nullptr) && (ws_size >= KEYS_BF + W2_BF);

    k0_zero   <<<dim3(128),       256, 0, stream>>>(out);
    k1_qproj  <<<dim3(16, 4),     256, 0, stream>>>(query, W1, out);
    if (use_ws) {
        short* keysp = (short*)d_ws;
        short* W2p   = keysp + KEYS_BF / 2;   // 16B-aligned
        k_pack<<<dim3(2048), 256, 0, stream>>>(keys, keysp, 8388608);   // 64*1024*1024/8
        k_pack<<<dim3(512),  256, 0, stream>>>(W2,   W2p,   131072);    // 1024*1024/8
        k2_scores_direct<<<dim3(8, 8, 64), 256, 0, stream>>>(keysp, W2p, v, out);
    } else {
        k2_scores       <<<dim3(8, 8, 64), 256, 0, stream>>>(keys, W2, v, out);
    }
    k3_softmax<<<dim3(64),        256, 0, stream>>>(mask, out);
    k4_context<<<dim3(8, 64),     256, 0, stream>>>(keys, out);
}